// Round 13
// baseline (194.572 us; speedup 1.0000x reference)
//
#include <hip/hip_runtime.h>
#include <hip/hip_fp16.h>
#include <math.h>
#include <stdint.h>

#define NH    8
#define HD    64
#define NTOK  4096   // D*H*W = 16^3
#define CDIM  512
#define NSAMP 27

typedef __attribute__((ext_vector_type(8))) _Float16 half8;
typedef __attribute__((ext_vector_type(4))) float floatx4;
typedef unsigned short ushort_t;

__device__ __forceinline__ ushort_t f16b(float f) {
  return __half_as_ushort(__float2half(f));
}
__device__ __forceinline__ __half2 u2h2(uint32_t u) { return __builtin_bit_cast(__half2, u); }
__device__ __forceinline__ uint32_t h22u(__half2 h) { return __builtin_bit_cast(uint32_t, h); }

// Full 64-lane sum via DPP; result uniform via readlane(63)  [R8 form]
__device__ __forceinline__ float wave_sum_bcast(float x) {
#define DPP_STEP(ctrl, rmask)                                                   \
  { int t = __builtin_amdgcn_update_dpp(0, __float_as_int(x), ctrl, rmask, 0xf, \
                                        true);                                  \
    x += __int_as_float(t); }
  DPP_STEP(0x111, 0xf)  // row_shr:1
  DPP_STEP(0x112, 0xf)  // row_shr:2
  DPP_STEP(0x114, 0xf)  // row_shr:4
  DPP_STEP(0x118, 0xf)  // row_shr:8
  DPP_STEP(0x142, 0xa)  // row_bcast:15
  DPP_STEP(0x143, 0xc)  // row_bcast:31 -> lane63 = total
#undef DPP_STEP
  return __int_as_float(__builtin_amdgcn_readlane(__float_as_int(x), 63));
}

// ============ Kernel 0: fp32 -> f16 for x, w_qkv, w_proj ============
__global__ __launch_bounds__(256) void k_cvt(const float4* __restrict__ x,
                                             const float4* __restrict__ wq,
                                             const float4* __restrict__ wp,
                                             ushort_t* __restrict__ xb,
                                             ushort_t* __restrict__ wqb,
                                             ushort_t* __restrict__ wpb) {
  int i = blockIdx.x * 256 + threadIdx.x;   // float4 index
  const float4* src; ushort_t* dst; int off;
  if (i < 524288)      { src = x;  dst = xb;  off = i; }
  else if (i < 720896) { src = wq; dst = wqb; off = i - 524288; }
  else                 { src = wp; dst = wpb; off = i - 720896; }
  float4 v = src[off];
  ushort4 o = make_ushort4(f16b(v.x), f16b(v.y), f16b(v.z), f16b(v.w));
  *(ushort4*)&dst[(size_t)off * 4] = o;
}

// ============ Kernel 0b: combined-weight prep ============
// blocks 0..383: woffd[768][512] f16 block-diagonal offset weights
//   row r = h*81+j (r<648): woffd[r][K] = w_off[j][K-h*64] if K in h-range else 0
// blocks 384..1407: wrelall[1024][512] f16: row c = h*126+j (c<1008):
//   wrelall[c][K] = sum_d relcat[j][d] * w_qkv[h*64+d][K]   (relcat = [rel_w;rel_h;rel_d])
__global__ __launch_bounds__(256) void k_wpre(const float* __restrict__ w_qkv,
                                              const float* __restrict__ w_off,
                                              const float* __restrict__ rel_d,
                                              const float* __restrict__ rel_h,
                                              const float* __restrict__ rel_w,
                                              ushort_t* __restrict__ woffd,
                                              ushort_t* __restrict__ wrelall) {
  const int b = blockIdx.x, tid = threadIdx.x;
  if (b < 384) {
    int i = b * 256 + tid;              // ushort4 index into woffd (98304 total)
    int e = i * 4;
    int r = e >> 9, K = e & 511;        // K multiple of 4
    float4 v = make_float4(0.f, 0.f, 0.f, 0.f);
    if (r < 648) {
      int h = r / 81, j = r - h * 81;
      int kb = K - h * 64;
      if (kb >= 0 && kb < 64) v = *(const float4*)&w_off[j * 64 + kb];
    }
    ushort4 o = make_ushort4(f16b(v.x), f16b(v.y), f16b(v.z), f16b(v.w));
    *(ushort4*)&woffd[(size_t)e] = o;
  } else {
    int row = b - 384;                  // 0..1023
    ushort_t* dst = wrelall + (size_t)row * 512;
    if (row >= 1008) { dst[tid] = 0; dst[tid + 256] = 0; return; }
    int h = row / 126, j = row - h * 126;
    const float* relrow = (j < 42) ? (rel_w + j * 64)
                        : (j < 84) ? (rel_h + (j - 42) * 64)
                                   : (rel_d + (j - 84) * 64);
    __shared__ float rl[64];
    if (tid < 64) rl[tid] = relrow[tid];
    __syncthreads();
    float a0 = 0.f, a1 = 0.f;
#pragma unroll 8
    for (int d = 0; d < 64; d++) {
      const float* wr = &w_qkv[(size_t)(h * 64 + d) * 512];
      a0 = fmaf(rl[d], wr[tid], a0);
      a1 = fmaf(rl[d], wr[tid + 256], a1);
    }
    dst[tid] = f16b(a0);
    dst[tid + 256] = f16b(a1);
  }
}

// ============ Kernel 1: MEGA GEMM — qkv + offsets + pos in one pass ============
// C = xh(4096x512) @ B^T. bn 0..3: q col-tiles -> qh16 (coalesced b128).
// bn 4..11: head h=bn-4 kv tile (k rows 512+64h, v rows 1024+64h) -> packed kv
// dwords, coalesced dwordx4. bn 12..17: offset cols (woffd) -> ob fp32.
// bn 18..25: pos cols (wrelall) -> Pb fp32.
__global__ __launch_bounds__(256) void k_mega(const ushort_t* __restrict__ Ah,
                                              const ushort_t* __restrict__ wqh,
                                              const ushort_t* __restrict__ woffd,
                                              const ushort_t* __restrict__ wrelall,
                                              ushort_t* __restrict__ qh16,
                                              uint32_t* __restrict__ kvb,
                                              float* __restrict__ ob,
                                              float* __restrict__ Pb) {
  __shared__ __align__(16) ushort_t As[128 * 32];
  __shared__ __align__(16) ushort_t Bs[128 * 32];
  __shared__ __align__(16) ushort_t Cs[128 * 136];   // only used by bn < 12
  const int tid = threadIdx.x;
  const int wave = tid >> 6, lane = tid & 63;
  const int wr = wave >> 1, wc = wave & 1;
  const int m15 = lane & 15, quad = lane >> 4;
  const int bm = blockIdx.x, bn = blockIdx.y;
  floatx4 acc[4][4];
#pragma unroll
  for (int i = 0; i < 4; i++)
#pragma unroll
    for (int j = 0; j < 4; j++) acc[i][j] = {0.f, 0.f, 0.f, 0.f};

  const int r0 = tid >> 2, c0 = (tid & 3) * 8;
  const int r1 = r0 + 64;
  const ushort_t* Bp;
  int baseA, baseB;
  if (bn < 4)       { Bp = wqh;     baseA = bn * 128 + r0;            baseB = bn * 128 + r1; }
  else if (bn < 12) { Bp = wqh;     baseA = 512 + (bn - 4) * 64 + r0; baseB = 1024 + (bn - 4) * 64 + r0; }
  else if (bn < 18) { Bp = woffd;   baseA = (bn - 12) * 128 + r0;     baseB = (bn - 12) * 128 + r1; }
  else              { Bp = wrelall; baseA = (bn - 18) * 128 + r0;     baseB = (bn - 18) * 128 + r1; }

  for (int k0 = 0; k0 < 512; k0 += 32) {
    *(uint4*)&As[r0 * 32 + c0] = *(const uint4*)&Ah[(size_t)(bm * 128 + r0) * 512 + k0 + c0];
    *(uint4*)&As[r1 * 32 + c0] = *(const uint4*)&Ah[(size_t)(bm * 128 + r1) * 512 + k0 + c0];
    *(uint4*)&Bs[r0 * 32 + c0] = *(const uint4*)&Bp[(size_t)baseA * 512 + k0 + c0];
    *(uint4*)&Bs[r1 * 32 + c0] = *(const uint4*)&Bp[(size_t)baseB * 512 + k0 + c0];
    __syncthreads();
    half8 af[4], bf[4];
#pragma unroll
    for (int i = 0; i < 4; i++)
      af[i] = *(const half8*)&As[(wr * 64 + i * 16 + m15) * 32 + quad * 8];
#pragma unroll
    for (int j = 0; j < 4; j++)
      bf[j] = *(const half8*)&Bs[(wc * 64 + j * 16 + m15) * 32 + quad * 8];
#pragma unroll
    for (int i = 0; i < 4; i++)
#pragma unroll
      for (int j = 0; j < 4; j++)
        acc[i][j] = __builtin_amdgcn_mfma_f32_16x16x32_f16(af[i], bf[j], acc[i][j], 0, 0, 0);
    __syncthreads();
  }

  if (bn < 12) {
    // stage C-tile to LDS as f16, then coalesced stores
#pragma unroll
    for (int i = 0; i < 4; i++)
#pragma unroll
      for (int j = 0; j < 4; j++) {
        int col = wc * 64 + j * 16 + m15;
#pragma unroll
        for (int r = 0; r < 4; r++) {
          int row = wr * 64 + i * 16 + quad * 4 + r;
          Cs[row * 136 + col] = f16b(acc[i][j][r]);
        }
      }
    __syncthreads();
    if (bn < 4) {
#pragma unroll
      for (int it = 0; it < 8; it++) {
        int id = it * 256 + tid;
        int hh = id >> 10, row = (id >> 3) & 127, chunk = id & 7;
        uint4 d = *(const uint4*)&Cs[row * 136 + hh * 64 + chunk * 8];
        int hq = bn * 2 + hh;
        *(uint4*)&qh16[((size_t)hq * NTOK + bm * 128 + row) * 64 + chunk * 8] = d;
      }
    } else {
      const int h = bn - 4;
#pragma unroll
      for (int it = 0; it < 8; it++) {
        int id = it * 256 + tid;
        int row = id >> 4, chunk = id & 15;
        uint2 kk = *(const uint2*)&Cs[row * 136 + chunk * 4];        // 4 k-halves
        uint2 vv = *(const uint2*)&Cs[row * 136 + 64 + chunk * 4];   // 4 v-halves
        uint4 o;
        o.x = (kk.x & 0xffffu) | (vv.x << 16);
        o.y = (kk.x >> 16) | (vv.x & 0xffff0000u);
        o.z = (kk.y & 0xffffu) | (vv.y << 16);
        o.w = (kk.y >> 16) | (vv.y & 0xffff0000u);
        *(uint4*)&kvb[((size_t)h * NTOK + bm * 128 + row) * 64 + chunk * 4] = o;
      }
    }
  } else if (bn < 18) {
    const int cbase = (bn - 12) * 128;
#pragma unroll
    for (int i = 0; i < 4; i++)
#pragma unroll
      for (int j = 0; j < 4; j++) {
        int col = cbase + wc * 64 + j * 16 + m15;
        if (col < 648) {
          int h = col / 81, j81 = col - h * 81;
#pragma unroll
          for (int r = 0; r < 4; r++) {
            int row = bm * 128 + wr * 64 + i * 16 + quad * 4 + r;
            ob[((size_t)h * NTOK + row) * 81 + j81] = acc[i][j][r];
          }
        }
      }
  } else {
    const int cbase = (bn - 18) * 128;
#pragma unroll
    for (int i = 0; i < 4; i++)
#pragma unroll
      for (int j = 0; j < 4; j++) {
        int col = cbase + wc * 64 + j * 16 + m15;
        if (col < 1008) {
          int h = col / 126, jj = col - h * 126;
#pragma unroll
          for (int r = 0; r < 4; r++) {
            int row = bm * 128 + wr * 64 + i * 16 + quad * 4 + r;
            Pb[((size_t)h * NTOK + row) * 126 + jj] = acc[i][j][r];
          }
        }
      }
  }
}

// ============ Kernel 2: fused deformable attention — exact R8/R12 structure ============
__global__ __launch_bounds__(256) void k_attn(const ushort_t* __restrict__ qh16,
                                              const uint32_t* __restrict__ kvb,
                                              const float* __restrict__ obuf,
                                              const float* __restrict__ Pbuf,
                                              ushort_t* __restrict__ attb16) {
  __shared__ int      s_off[4][NSAMP][8];   // BYTE offsets (voxel*256)
  __shared__ uint32_t s_cwh[4][NSAMP][8];   // half2(w,w) splats
  __shared__ uint32_t vpair[4][14][64];     // half2(v[2p], v[2p+1]) per channel
  __shared__ uint32_t s_wp[4][14];          // half2(w[2p], w[2p+1])
  const int bid = blockIdx.x;
  const int h = bid & 7;
  const int wave = threadIdx.x >> 6;
  const int lane = threadIdx.x & 63;
  const int n = (bid >> 3) * 4 + wave;
  const int z = n >> 8, y = (n >> 4) & 15, xq = n & 15;
  const float qd = __half2float(__ushort_as_half(qh16[((size_t)h * NTOK + n) * 64 + lane]));
  const char* kvc = (const char*)(kvb + (size_t)h * NTOK * 64);
  const uint32_t lane4 = (uint32_t)lane * 4u;

  if (lane < NSAMP) {
    const int s = lane;
    const float* op = &obuf[((size_t)h * NTOK + n) * 81 + s * 3];
    float oz = op[0], oy = op[1], ox = op[2];
    float pz = (float)(z + (s / 9) - 1) + oz;
    float py = (float)(y + ((s / 3) % 3) - 1) + oy;
    float px = (float)(xq + (s % 3) - 1) + ox;
    float fz = floorf(pz), fy = floorf(py), fx = floorf(px);
    float wz = pz - fz, wy = py - fy, wx = px - fx;
    int z0 = (int)fz, y0 = (int)fy, x0 = (int)fx;
    int      oarr[8];
    uint32_t warr[8];
#pragma unroll
    for (int c = 0; c < 8; c++) {
      int dz = (c >> 2) & 1, dy = (c >> 1) & 1, dx = c & 1;
      int zi = z0 + dz, yi = y0 + dy, xi = x0 + dx;
      bool valid = (zi >= 0) && (zi < 16) && (yi >= 0) && (yi < 16) && (xi >= 0) && (xi < 16);
      float w = (dz ? wz : 1.f - wz) * (dy ? wy : 1.f - wy) * (dx ? wx : 1.f - wx);
      int zc = min(max(zi, 0), 15), yc = min(max(yi, 0), 15), xc = min(max(xi, 0), 15);
      oarr[c] = ((zc * 16 + yc) * 16 + xc) * 256;       // byte offset of voxel row
      uint32_t hw = (uint32_t)f16b(valid ? w : 0.f);
      warr[c] = hw | (hw << 16);                        // half2(w, w)
    }
    *(int4*)&s_off[wave][s][0]  = make_int4(oarr[0], oarr[1], oarr[2], oarr[3]);
    *(int4*)&s_off[wave][s][4]  = make_int4(oarr[4], oarr[5], oarr[6], oarr[7]);
    *(uint4*)&s_cwh[wave][s][0] = make_uint4(warr[0], warr[1], warr[2], warr[3]);
    *(uint4*)&s_cwh[wave][s][4] = make_uint4(warr[4], warr[5], warr[6], warr[7]);
  }
  // no __syncthreads: producers/consumers are the same wave (in-order ds)

  float mydot = 0.f;
  uint32_t prev_acc = 0;
#pragma unroll 2
  for (int s = 0; s < NSAMP; s++) {
    int4  o0 = *(const int4*)&s_off[wave][s][0];
    int4  o1 = *(const int4*)&s_off[wave][s][4];
    uint4 c0 = *(const uint4*)&s_cwh[wave][s][0];
    uint4 c1 = *(const uint4*)&s_cwh[wave][s][4];
    __half2 acc2 = u2h2(0u);
    uint32_t p;
#define CORNER(OV, WV)                                                       \
    p = *(const uint32_t*)(kvc + (uint32_t)((uint32_t)OV + lane4));          \
    acc2 = __hfma2(u2h2(WV), u2h2(p), acc2);
    CORNER(o0.x, c0.x) CORNER(o0.y, c0.y) CORNER(o0.z, c0.z) CORNER(o0.w, c0.w)
    CORNER(o1.x, c1.x) CORNER(o1.y, c1.y) CORNER(o1.z, c1.z) CORNER(o1.w, c1.w)
#undef CORNER
    float ak = __half2float(acc2.x);
    float tot = wave_sum_bcast(qd * ak);   // uniform (SGPR)
    mydot = (lane == s) ? tot : mydot;
    uint32_t au = h22u(acc2);
    if (s & 1)
      vpair[wave][s >> 1][lane] = (prev_acc >> 16) | (au & 0xffff0000u);
    else
      prev_acc = au;
  }
  vpair[wave][13][lane] = prev_acc >> 16;   // v[26] in low half, 0 in high

  float logit = -INFINITY;
  if (lane < NSAMP) {
    int j = 15 + lane - xq;
    int n2 = (z * 16 + xq) * 16 + y;
    int n3 = (xq * 16 + z) * 16 + y;
    float pos = Pbuf[((size_t)h * NTOK + n) * 126 + j]
              + Pbuf[((size_t)h * NTOK + n2) * 126 + 42 + j]
              + Pbuf[((size_t)h * NTOK + n3) * 126 + 84 + j];
    logit = mydot * 0.125f + pos;
  }

  float mx = logit;
#pragma unroll
  for (int off = 32; off >= 1; off >>= 1) mx = fmaxf(mx, __shfl_xor(mx, off, 64));
  float e = __expf(logit - mx);            // lanes >= 27: exp(-inf) = 0
  float sum = e;
#pragma unroll
  for (int off = 32; off >= 1; off >>= 1) sum += __shfl_xor(sum, off, 64);
  const float wgt = e / sum;
  uint32_t hw = (uint32_t)f16b(wgt);                       // lanes>=27 -> 0
  uint32_t nw = (uint32_t)__shfl_down((int)hw, 1, 64);     // next lane's weight
  if ((lane & 1) == 0 && lane < 28)
    s_wp[wave][lane >> 1] = hw | (nw << 16);

  __half2 out2 = u2h2(0u);
#pragma unroll
  for (int p2 = 0; p2 < 14; p2++) {
    __half2 v2 = u2h2(vpair[wave][p2][lane]);
    __half2 w2 = u2h2(s_wp[wave][p2]);
    out2 = __hfma2(w2, v2, out2);
  }
  float out = __half2float(out2.x) + __half2float(out2.y);
  attb16[(size_t)n * 512 + h * 64 + lane] = f16b(out);
}

// ============ Kernel 3: proj GEMM via MFMA f16: out = attb @ w_proj^T + b ============
__global__ __launch_bounds__(256) void k_proj(const ushort_t* __restrict__ Ah,
                                              const ushort_t* __restrict__ Bth,
                                              const float* __restrict__ bias,
                                              float* __restrict__ out) {
  __shared__ __align__(16) ushort_t As[128 * 32];
  __shared__ __align__(16) ushort_t Bs[128 * 32];
  const int tid = threadIdx.x;
  const int wave = tid >> 6, lane = tid & 63;
  const int wr = wave >> 1, wc = wave & 1;
  const int m15 = lane & 15, quad = lane >> 4;
  const int bm = blockIdx.x, bn = blockIdx.y;
  floatx4 acc[4][4];
#pragma unroll
  for (int i = 0; i < 4; i++)
#pragma unroll
    for (int j = 0; j < 4; j++) acc[i][j] = {0.f, 0.f, 0.f, 0.f};

  const int r0 = tid >> 2, c0 = (tid & 3) * 8;
  const int r1 = r0 + 64;
  for (int k0 = 0; k0 < 512; k0 += 32) {
    *(uint4*)&As[r0 * 32 + c0] = *(const uint4*)&Ah[(size_t)(bm * 128 + r0) * 512 + k0 + c0];
    *(uint4*)&As[r1 * 32 + c0] = *(const uint4*)&Ah[(size_t)(bm * 128 + r1) * 512 + k0 + c0];
    *(uint4*)&Bs[r0 * 32 + c0] = *(const uint4*)&Bth[(size_t)(bn * 128 + r0) * 512 + k0 + c0];
    *(uint4*)&Bs[r1 * 32 + c0] = *(const uint4*)&Bth[(size_t)(bn * 128 + r1) * 512 + k0 + c0];
    __syncthreads();
    half8 af[4], bf[4];
#pragma unroll
    for (int i = 0; i < 4; i++)
      af[i] = *(const half8*)&As[(wr * 64 + i * 16 + m15) * 32 + quad * 8];
#pragma unroll
    for (int j = 0; j < 4; j++)
      bf[j] = *(const half8*)&Bs[(wc * 64 + j * 16 + m15) * 32 + quad * 8];
#pragma unroll
    for (int i = 0; i < 4; i++)
#pragma unroll
      for (int j = 0; j < 4; j++)
        acc[i][j] = __builtin_amdgcn_mfma_f32_16x16x32_f16(af[i], bf[j], acc[i][j], 0, 0, 0);
    __syncthreads();
  }

#pragma unroll
  for (int i = 0; i < 4; i++)
#pragma unroll
    for (int j = 0; j < 4; j++) {
      int col = bn * 128 + wc * 64 + j * 16 + m15;
      float b = bias[col];
#pragma unroll
      for (int r = 0; r < 4; r++) {
        int row = bm * 128 + wr * 64 + i * 16 + quad * 4 + r;
        out[(size_t)row * 512 + col] = acc[i][j][r] + b;
      }
    }
}

extern "C" void kernel_launch(void* const* d_in, const int* in_sizes, int n_in,
                              void* d_out, int out_size, void* d_ws, size_t ws_size,
                              hipStream_t stream) {
  const float* x      = (const float*)d_in[0];
  const float* w_qkv  = (const float*)d_in[1];
  const float* w_proj = (const float*)d_in[2];
  const float* b_proj = (const float*)d_in[3];
  const float* w_off  = (const float*)d_in[4];
  const float* rel_d  = (const float*)d_in[5];
  const float* rel_h  = (const float*)d_in[6];
  const float* rel_w  = (const float*)d_in[7];

  char* ws = (char*)d_ws;
  uint32_t* kvb     = (uint32_t*)ws; ws += (size_t)NH * NTOK * 64 * 4;
  float*    ob      = (float*)ws;    ws += (size_t)NH * NTOK * 81 * 4;
  float*    Pb      = (float*)ws;    ws += (size_t)NH * NTOK * 126 * 4;
  ushort_t* attb16  = (ushort_t*)ws; ws += (size_t)NTOK * CDIM * 2;
  ushort_t* xh      = (ushort_t*)ws; ws += (size_t)NTOK * CDIM * 2;
  ushort_t* wqh     = (ushort_t*)ws; ws += (size_t)3 * CDIM * CDIM * 2;
  ushort_t* wph     = (ushort_t*)ws; ws += (size_t)CDIM * CDIM * 2;
  ushort_t* qh16    = (ushort_t*)ws; ws += (size_t)NH * NTOK * 64 * 2;
  ushort_t* woffd   = (ushort_t*)ws; ws += (size_t)768 * 512 * 2;
  ushort_t* wrelall = (ushort_t*)ws; ws += (size_t)1024 * 512 * 2;
  float*    out     = (float*)d_out;

  k_cvt <<<dim3(3072), dim3(256), 0, stream>>>((const float4*)x, (const float4*)w_qkv,
                                               (const float4*)w_proj, xh, wqh, wph);
  k_wpre<<<dim3(1408), dim3(256), 0, stream>>>(w_qkv, w_off, rel_d, rel_h, rel_w,
                                               woffd, wrelall);
  k_mega<<<dim3(32, 26), dim3(256), 0, stream>>>(xh, wqh, woffd, wrelall,
                                                 qh16, kvb, ob, Pb);
  k_attn<<<dim3(8192),  dim3(256), 0, stream>>>(qh16, kvb, ob, Pb, attb16);
  k_proj<<<dim3(32, 4), dim3(256), 0, stream>>>(attb16, wph, b_proj, out);
}

// Round 14
// 174.226 us; speedup vs baseline: 1.1168x; 1.1168x over previous
//
#include <hip/hip_runtime.h>
#include <hip/hip_fp16.h>
#include <math.h>
#include <stdint.h>

#define NH    8
#define HD    64
#define NTOK  4096   // D*H*W = 16^3
#define CDIM  512
#define NSAMP 27

typedef __attribute__((ext_vector_type(8))) _Float16 half8;
typedef __attribute__((ext_vector_type(4))) float floatx4;
typedef unsigned short ushort_t;

__device__ __forceinline__ ushort_t f16b(float f) {
  return __half_as_ushort(__float2half(f));
}
__device__ __forceinline__ __half2 u2h2(uint32_t u) { return __builtin_bit_cast(__half2, u); }
__device__ __forceinline__ uint32_t h22u(__half2 h) { return __builtin_bit_cast(uint32_t, h); }

// Full 64-lane sum via DPP; result uniform via readlane(63)  [R8 form]
__device__ __forceinline__ float wave_sum_bcast(float x) {
#define DPP_STEP(ctrl, rmask)                                                   \
  { int t = __builtin_amdgcn_update_dpp(0, __float_as_int(x), ctrl, rmask, 0xf, \
                                        true);                                  \
    x += __int_as_float(t); }
  DPP_STEP(0x111, 0xf)  // row_shr:1
  DPP_STEP(0x112, 0xf)  // row_shr:2
  DPP_STEP(0x114, 0xf)  // row_shr:4
  DPP_STEP(0x118, 0xf)  // row_shr:8
  DPP_STEP(0x142, 0xa)  // row_bcast:15
  DPP_STEP(0x143, 0xc)  // row_bcast:31 -> lane63 = total
#undef DPP_STEP
  return __int_as_float(__builtin_amdgcn_readlane(__float_as_int(x), 63));
}

// ============ Kernel 0: fp32 -> f16 for x, w_qkv, w_proj, w_off, rel_* ============
__global__ __launch_bounds__(256) void k_cvt(const float* __restrict__ x,
                                             const float* __restrict__ wq,
                                             const float* __restrict__ wp,
                                             const float* __restrict__ w_off,
                                             const float* __restrict__ rel_d,
                                             const float* __restrict__ rel_h,
                                             const float* __restrict__ rel_w,
                                             ushort_t* __restrict__ xb,
                                             ushort_t* __restrict__ wqb,
                                             ushort_t* __restrict__ wpb,
                                             ushort_t* __restrict__ w_offh,
                                             ushort_t* __restrict__ relh) {
  int i = blockIdx.x * 256 + threadIdx.x;   // float4 index
  const float4* src = nullptr;
  ushort_t* dst;
  int off;
  float4 v = make_float4(0.f, 0.f, 0.f, 0.f);
  if (i < 524288)      { src = (const float4*)x;  dst = xb;  off = i; }
  else if (i < 720896) { src = (const float4*)wq; dst = wqb; off = i - 524288; }
  else if (i < 786432) { src = (const float4*)wp; dst = wpb; off = i - 720896; }
  else {
    int t = i - 786432;             // 0..4095
    if (t < 2048) {                 // w_offh [128][64], rows >= 81 zero
      off = t;
      int e = t * 4, row = e >> 6;
      if (row < 81) v = *(const float4*)&w_off[e];
      dst = w_offh;
    } else {                        // relh [128][64]: w | h | d | zero
      off = t - 2048;
      int e = off * 4, row = e >> 6, col = e & 63;
      if (row < 42)       v = *(const float4*)&rel_w[row * 64 + col];
      else if (row < 84)  v = *(const float4*)&rel_h[(row - 42) * 64 + col];
      else if (row < 126) v = *(const float4*)&rel_d[(row - 84) * 64 + col];
      dst = relh;
    }
  }
  if (src) v = src[off];
  ushort4 o = make_ushort4(f16b(v.x), f16b(v.y), f16b(v.z), f16b(v.w));
  *(ushort4*)&dst[(size_t)off * 4] = o;
}

// ============ Kernel 1: qkv GEMM, 64x128 tiles (grid 64x12 = 768 blocks, 3/CU) ============
// bn 0..3: q col-tiles. bn 4..11: head h=bn-4 kv tile (k rows 512+64h, v rows
// 1024+64h) -> packed kv dwords, coalesced. Waves 2x2; each wave 32x64 (acc 2x4).
__global__ __launch_bounds__(256) void k_qkv(const ushort_t* __restrict__ Ah,
                                             const ushort_t* __restrict__ Bth,
                                             ushort_t* __restrict__ qh16,
                                             uint32_t* __restrict__ kvb) {
  __shared__ __align__(16) ushort_t As[64 * 32];
  __shared__ __align__(16) ushort_t Bs[128 * 32];
  __shared__ __align__(16) ushort_t Cs[64 * 136];
  const int tid = threadIdx.x;
  const int wave = tid >> 6, lane = tid & 63;
  const int wr = wave >> 1, wc = wave & 1;
  const int m15 = lane & 15, quad = lane >> 4;
  const int bm = blockIdx.x, bn = blockIdx.y;
  const bool is_q = (bn < 4);
  const int h = bn - 4;
  floatx4 acc[2][4];
#pragma unroll
  for (int i = 0; i < 2; i++)
#pragma unroll
    for (int j = 0; j < 4; j++) acc[i][j] = {0.f, 0.f, 0.f, 0.f};

  const int r0 = tid >> 2, c0 = (tid & 3) * 8;   // A: 1 chunk/thread; B: 2
  const int brA = is_q ? (bn * 128 + r0) : (512 + h * 64 + r0);
  const int brB = is_q ? (bn * 128 + 64 + r0) : (1024 + h * 64 + r0);
  for (int k0 = 0; k0 < 512; k0 += 32) {
    *(uint4*)&As[r0 * 32 + c0] = *(const uint4*)&Ah[(size_t)(bm * 64 + r0) * 512 + k0 + c0];
    *(uint4*)&Bs[r0 * 32 + c0]        = *(const uint4*)&Bth[(size_t)brA * 512 + k0 + c0];
    *(uint4*)&Bs[(r0 + 64) * 32 + c0] = *(const uint4*)&Bth[(size_t)brB * 512 + k0 + c0];
    __syncthreads();
    half8 af[2], bf[4];
#pragma unroll
    for (int i = 0; i < 2; i++)
      af[i] = *(const half8*)&As[(wr * 32 + i * 16 + m15) * 32 + quad * 8];
#pragma unroll
    for (int j = 0; j < 4; j++)
      bf[j] = *(const half8*)&Bs[(wc * 64 + j * 16 + m15) * 32 + quad * 8];
#pragma unroll
    for (int i = 0; i < 2; i++)
#pragma unroll
      for (int j = 0; j < 4; j++)
        acc[i][j] = __builtin_amdgcn_mfma_f32_16x16x32_f16(af[i], bf[j], acc[i][j], 0, 0, 0);
    __syncthreads();
  }

  // stage C-tile (64 rows x 128 cols) to LDS as f16
#pragma unroll
  for (int i = 0; i < 2; i++)
#pragma unroll
    for (int j = 0; j < 4; j++) {
      int col = wc * 64 + j * 16 + m15;
#pragma unroll
      for (int r = 0; r < 4; r++) {
        int row = wr * 32 + i * 16 + quad * 4 + r;
        Cs[row * 136 + col] = f16b(acc[i][j][r]);
      }
    }
  __syncthreads();

  if (is_q) {
    // 1024 16B-chunks: id = hh*512 + row*8 + chunk
#pragma unroll
    for (int it = 0; it < 4; it++) {
      int id = it * 256 + tid;
      int hh = id >> 9, row = (id >> 3) & 63, chunk = id & 7;
      uint4 d = *(const uint4*)&Cs[row * 136 + hh * 64 + chunk * 8];
      int hq = bn * 2 + hh;
      *(uint4*)&qh16[((size_t)hq * NTOK + bm * 64 + row) * 64 + chunk * 8] = d;
    }
  } else {
    // 1024 dwordx4 chunks of packed (k | v<<16): id = row*16 + chunk
#pragma unroll
    for (int it = 0; it < 4; it++) {
      int id = it * 256 + tid;
      int row = id >> 4, chunk = id & 15;
      uint2 kk = *(const uint2*)&Cs[row * 136 + chunk * 4];
      uint2 vv = *(const uint2*)&Cs[row * 136 + 64 + chunk * 4];
      uint4 o;
      o.x = (kk.x & 0xffffu) | (vv.x << 16);
      o.y = (kk.x >> 16) | (vv.x & 0xffff0000u);
      o.z = (kk.y & 0xffffu) | (vv.y << 16);
      o.w = (kk.y >> 16) | (vv.y & 0xffff0000u);
      *(uint4*)&kvb[((size_t)h * NTOK + bm * 64 + row) * 64 + chunk * 4] = o;
    }
  }
}

// ============ Kernel 2: merged off/pos GEMMs via MFMA f16 (unchanged, K=64) ============
__global__ __launch_bounds__(256) void k_aux(const ushort_t* __restrict__ xh,
                                             const ushort_t* __restrict__ qh16,
                                             const ushort_t* __restrict__ w_offh,
                                             const ushort_t* __restrict__ relh,
                                             float* __restrict__ ob,
                                             float* __restrict__ Pb) {
  __shared__ __align__(16) ushort_t As[128 * 32];
  __shared__ __align__(16) ushort_t Bs[128 * 32];
  const int tid = threadIdx.x;
  const int wave = tid >> 6, lane = tid & 63;
  const int wr = wave >> 1, wc = wave & 1;
  const int m15 = lane & 15, quad = lane >> 4;
  const int bm = blockIdx.x;
  const int mode = blockIdx.y >> 3, h = blockIdx.y & 7;

  const ushort_t* A;  int lda;
  const ushort_t* B;
  float* C;  int NC;
  if (mode == 0) { A = xh + h * 64;                  lda = 512; B = w_offh; C = ob + (size_t)h * NTOK * 81;  NC = 81; }
  else           { A = qh16 + (size_t)h * NTOK * 64; lda = 64;  B = relh;   C = Pb + (size_t)h * NTOK * 126; NC = 126; }

  floatx4 acc[4][4];
#pragma unroll
  for (int i = 0; i < 4; i++)
#pragma unroll
    for (int j = 0; j < 4; j++) acc[i][j] = {0.f, 0.f, 0.f, 0.f};

  const int r0 = tid >> 2, c0 = (tid & 3) * 8;
  const int r1 = r0 + 64;
  for (int k0 = 0; k0 < 64; k0 += 32) {
    *(uint4*)&As[r0 * 32 + c0] = *(const uint4*)&A[(size_t)(bm * 128 + r0) * lda + k0 + c0];
    *(uint4*)&As[r1 * 32 + c0] = *(const uint4*)&A[(size_t)(bm * 128 + r1) * lda + k0 + c0];
    *(uint4*)&Bs[r0 * 32 + c0] = *(const uint4*)&B[(size_t)r0 * 64 + k0 + c0];
    *(uint4*)&Bs[r1 * 32 + c0] = *(const uint4*)&B[(size_t)r1 * 64 + k0 + c0];
    __syncthreads();
    half8 af[4], bf[4];
#pragma unroll
    for (int i = 0; i < 4; i++)
      af[i] = *(const half8*)&As[(wr * 64 + i * 16 + m15) * 32 + quad * 8];
#pragma unroll
    for (int j = 0; j < 4; j++)
      bf[j] = *(const half8*)&Bs[(wc * 64 + j * 16 + m15) * 32 + quad * 8];
#pragma unroll
    for (int i = 0; i < 4; i++)
#pragma unroll
      for (int j = 0; j < 4; j++)
        acc[i][j] = __builtin_amdgcn_mfma_f32_16x16x32_f16(af[i], bf[j], acc[i][j], 0, 0, 0);
    __syncthreads();
  }

#pragma unroll
  for (int i = 0; i < 4; i++)
#pragma unroll
    for (int j = 0; j < 4; j++) {
      int col = wc * 64 + j * 16 + m15;
      if (col < NC) {
#pragma unroll
        for (int r = 0; r < 4; r++) {
          int row = bm * 128 + wr * 64 + i * 16 + quad * 4 + r;
          C[(size_t)row * NC + col] = acc[i][j][r];
        }
      }
    }
}

// ============ Kernel 3: fused deformable attention — exact R8/R12 structure ============
__global__ __launch_bounds__(256) void k_attn(const ushort_t* __restrict__ qh16,
                                              const uint32_t* __restrict__ kvb,
                                              const float* __restrict__ obuf,
                                              const float* __restrict__ Pbuf,
                                              ushort_t* __restrict__ attb16) {
  __shared__ int      s_off[4][NSAMP][8];   // BYTE offsets (voxel*256)
  __shared__ uint32_t s_cwh[4][NSAMP][8];   // half2(w,w) splats
  __shared__ uint32_t vpair[4][14][64];     // half2(v[2p], v[2p+1]) per channel
  __shared__ uint32_t s_wp[4][14];          // half2(w[2p], w[2p+1])
  const int bid = blockIdx.x;
  const int h = bid & 7;
  const int wave = threadIdx.x >> 6;
  const int lane = threadIdx.x & 63;
  const int n = (bid >> 3) * 4 + wave;
  const int z = n >> 8, y = (n >> 4) & 15, xq = n & 15;
  const float qd = __half2float(__ushort_as_half(qh16[((size_t)h * NTOK + n) * 64 + lane]));
  const char* kvc = (const char*)(kvb + (size_t)h * NTOK * 64);
  const uint32_t lane4 = (uint32_t)lane * 4u;

  if (lane < NSAMP) {
    const int s = lane;
    const float* op = &obuf[((size_t)h * NTOK + n) * 81 + s * 3];
    float oz = op[0], oy = op[1], ox = op[2];
    float pz = (float)(z + (s / 9) - 1) + oz;
    float py = (float)(y + ((s / 3) % 3) - 1) + oy;
    float px = (float)(xq + (s % 3) - 1) + ox;
    float fz = floorf(pz), fy = floorf(py), fx = floorf(px);
    float wz = pz - fz, wy = py - fy, wx = px - fx;
    int z0 = (int)fz, y0 = (int)fy, x0 = (int)fx;
    int      oarr[8];
    uint32_t warr[8];
#pragma unroll
    for (int c = 0; c < 8; c++) {
      int dz = (c >> 2) & 1, dy = (c >> 1) & 1, dx = c & 1;
      int zi = z0 + dz, yi = y0 + dy, xi = x0 + dx;
      bool valid = (zi >= 0) && (zi < 16) && (yi >= 0) && (yi < 16) && (xi >= 0) && (xi < 16);
      float w = (dz ? wz : 1.f - wz) * (dy ? wy : 1.f - wy) * (dx ? wx : 1.f - wx);
      int zc = min(max(zi, 0), 15), yc = min(max(yi, 0), 15), xc = min(max(xi, 0), 15);
      oarr[c] = ((zc * 16 + yc) * 16 + xc) * 256;       // byte offset of voxel row
      uint32_t hw = (uint32_t)f16b(valid ? w : 0.f);
      warr[c] = hw | (hw << 16);                        // half2(w, w)
    }
    *(int4*)&s_off[wave][s][0]  = make_int4(oarr[0], oarr[1], oarr[2], oarr[3]);
    *(int4*)&s_off[wave][s][4]  = make_int4(oarr[4], oarr[5], oarr[6], oarr[7]);
    *(uint4*)&s_cwh[wave][s][0] = make_uint4(warr[0], warr[1], warr[2], warr[3]);
    *(uint4*)&s_cwh[wave][s][4] = make_uint4(warr[4], warr[5], warr[6], warr[7]);
  }
  // no __syncthreads: producers/consumers are the same wave (in-order ds)

  float mydot = 0.f;
  uint32_t prev_acc = 0;
#pragma unroll 2
  for (int s = 0; s < NSAMP; s++) {
    int4  o0 = *(const int4*)&s_off[wave][s][0];
    int4  o1 = *(const int4*)&s_off[wave][s][4];
    uint4 c0 = *(const uint4*)&s_cwh[wave][s][0];
    uint4 c1 = *(const uint4*)&s_cwh[wave][s][4];
    __half2 acc2 = u2h2(0u);
    uint32_t p;
#define CORNER(OV, WV)                                                       \
    p = *(const uint32_t*)(kvc + (uint32_t)((uint32_t)OV + lane4));          \
    acc2 = __hfma2(u2h2(WV), u2h2(p), acc2);
    CORNER(o0.x, c0.x) CORNER(o0.y, c0.y) CORNER(o0.z, c0.z) CORNER(o0.w, c0.w)
    CORNER(o1.x, c1.x) CORNER(o1.y, c1.y) CORNER(o1.z, c1.z) CORNER(o1.w, c1.w)
#undef CORNER
    float ak = __half2float(acc2.x);
    float tot = wave_sum_bcast(qd * ak);   // uniform (SGPR)
    mydot = (lane == s) ? tot : mydot;
    uint32_t au = h22u(acc2);
    if (s & 1)
      vpair[wave][s >> 1][lane] = (prev_acc >> 16) | (au & 0xffff0000u);
    else
      prev_acc = au;
  }
  vpair[wave][13][lane] = prev_acc >> 16;   // v[26] in low half, 0 in high

  float logit = -INFINITY;
  if (lane < NSAMP) {
    int j = 15 + lane - xq;
    int n2 = (z * 16 + xq) * 16 + y;
    int n3 = (xq * 16 + z) * 16 + y;
    float pos = Pbuf[((size_t)h * NTOK + n) * 126 + j]
              + Pbuf[((size_t)h * NTOK + n2) * 126 + 42 + j]
              + Pbuf[((size_t)h * NTOK + n3) * 126 + 84 + j];
    logit = mydot * 0.125f + pos;
  }

  float mx = logit;
#pragma unroll
  for (int off = 32; off >= 1; off >>= 1) mx = fmaxf(mx, __shfl_xor(mx, off, 64));
  float e = __expf(logit - mx);            // lanes >= 27: exp(-inf) = 0
  float sum = e;
#pragma unroll
  for (int off = 32; off >= 1; off >>= 1) sum += __shfl_xor(sum, off, 64);
  const float wgt = e / sum;
  uint32_t hw = (uint32_t)f16b(wgt);                       // lanes>=27 -> 0
  uint32_t nw = (uint32_t)__shfl_down((int)hw, 1, 64);     // next lane's weight
  if ((lane & 1) == 0 && lane < 28)
    s_wp[wave][lane >> 1] = hw | (nw << 16);

  __half2 out2 = u2h2(0u);
#pragma unroll
  for (int p2 = 0; p2 < 14; p2++) {
    __half2 v2 = u2h2(vpair[wave][p2][lane]);
    __half2 w2 = u2h2(s_wp[wave][p2]);
    out2 = __hfma2(w2, v2, out2);
  }
  float out = __half2float(out2.x) + __half2float(out2.y);
  attb16[(size_t)n * 512 + h * 64 + lane] = f16b(out);
}

// ============ Kernel 4: proj GEMM, 64x64 tiles (grid 64x8 = 512 blocks, 2/CU) ============
__global__ __launch_bounds__(256) void k_proj(const ushort_t* __restrict__ Ah,
                                              const ushort_t* __restrict__ Bth,
                                              const float* __restrict__ bias,
                                              float* __restrict__ out) {
  __shared__ __align__(16) ushort_t As[64 * 32];
  __shared__ __align__(16) ushort_t Bs[64 * 32];
  const int tid = threadIdx.x;
  const int wave = tid >> 6, lane = tid & 63;
  const int wr = wave >> 1, wc = wave & 1;
  const int m15 = lane & 15, quad = lane >> 4;
  const int bm = blockIdx.x, bn = blockIdx.y;
  floatx4 acc[2][2];
#pragma unroll
  for (int i = 0; i < 2; i++)
#pragma unroll
    for (int j = 0; j < 2; j++) acc[i][j] = {0.f, 0.f, 0.f, 0.f};

  const int r0 = tid >> 2, c0 = (tid & 3) * 8;   // 1 chunk/thread each
  for (int k0 = 0; k0 < 512; k0 += 32) {
    *(uint4*)&As[r0 * 32 + c0] = *(const uint4*)&Ah[(size_t)(bm * 64 + r0) * 512 + k0 + c0];
    *(uint4*)&Bs[r0 * 32 + c0] = *(const uint4*)&Bth[(size_t)(bn * 64 + r0) * 512 + k0 + c0];
    __syncthreads();
    half8 af[2], bf[2];
#pragma unroll
    for (int i = 0; i < 2; i++)
      af[i] = *(const half8*)&As[(wr * 32 + i * 16 + m15) * 32 + quad * 8];
#pragma unroll
    for (int j = 0; j < 2; j++)
      bf[j] = *(const half8*)&Bs[(wc * 32 + j * 16 + m15) * 32 + quad * 8];
#pragma unroll
    for (int i = 0; i < 2; i++)
#pragma unroll
      for (int j = 0; j < 2; j++)
        acc[i][j] = __builtin_amdgcn_mfma_f32_16x16x32_f16(af[i], bf[j], acc[i][j], 0, 0, 0);
    __syncthreads();
  }

#pragma unroll
  for (int i = 0; i < 2; i++)
#pragma unroll
    for (int j = 0; j < 2; j++) {
      int col = bn * 64 + wc * 32 + j * 16 + m15;
      float b = bias[col];
#pragma unroll
      for (int r = 0; r < 4; r++) {
        int row = bm * 64 + wr * 32 + i * 16 + quad * 4 + r;
        out[(size_t)row * 512 + col] = acc[i][j][r] + b;
      }
    }
}

extern "C" void kernel_launch(void* const* d_in, const int* in_sizes, int n_in,
                              void* d_out, int out_size, void* d_ws, size_t ws_size,
                              hipStream_t stream) {
  const float* x      = (const float*)d_in[0];
  const float* w_qkv  = (const float*)d_in[1];
  const float* w_proj = (const float*)d_in[2];
  const float* b_proj = (const float*)d_in[3];
  const float* w_off  = (const float*)d_in[4];
  const float* rel_d  = (const float*)d_in[5];
  const float* rel_h  = (const float*)d_in[6];
  const float* rel_w  = (const float*)d_in[7];

  char* ws = (char*)d_ws;
  uint32_t* kvb    = (uint32_t*)ws; ws += (size_t)NH * NTOK * 64 * 4;
  float*    ob     = (float*)ws;    ws += (size_t)NH * NTOK * 81 * 4;
  float*    Pb     = (float*)ws;    ws += (size_t)NH * NTOK * 126 * 4;
  ushort_t* attb16 = (ushort_t*)ws; ws += (size_t)NTOK * CDIM * 2;
  ushort_t* xh     = (ushort_t*)ws; ws += (size_t)NTOK * CDIM * 2;
  ushort_t* wqh    = (ushort_t*)ws; ws += (size_t)3 * CDIM * CDIM * 2;
  ushort_t* wph    = (ushort_t*)ws; ws += (size_t)CDIM * CDIM * 2;
  ushort_t* qh16   = (ushort_t*)ws; ws += (size_t)NH * NTOK * 64 * 2;
  ushort_t* w_offh = (ushort_t*)ws; ws += (size_t)128 * 64 * 2;
  ushort_t* relh   = (ushort_t*)ws; ws += (size_t)128 * 64 * 2;
  float*    out    = (float*)d_out;

  k_cvt <<<dim3(3088), dim3(256), 0, stream>>>(x, w_qkv, w_proj, w_off, rel_d, rel_h,
                                               rel_w, xh, wqh, wph, w_offh, relh);
  k_qkv <<<dim3(64, 12), dim3(256), 0, stream>>>(xh, wqh, qh16, kvb);
  k_aux <<<dim3(32, 16), dim3(256), 0, stream>>>(xh, qh16, w_offh, relh, ob, Pb);
  k_attn<<<dim3(8192),   dim3(256), 0, stream>>>(qh16, kvb, ob, Pb, attb16);
  k_proj<<<dim3(64, 8),  dim3(256), 0, stream>>>(attb16, wph, b_proj, out);
}